// Round 1
// baseline (2375.443 us; speedup 1.0000x reference)
//
#include <hip/hip_runtime.h>

#define Nn 50000
#define En 800000

static __device__ __forceinline__ float bf2f(unsigned int lo16) {
  return __uint_as_float(lo16 << 16);
}
static __device__ __forceinline__ unsigned short f2bf(float f) {
  unsigned int x = __float_as_uint(f);
  return (unsigned short)((x + 0x7FFFu + ((x >> 16) & 1u)) >> 16);
}

// ---------------- small utility kernels ----------------

// dst[k][c] = src[c][k], src is [128][K]
__global__ __launch_bounds__(256) void k_transpose(const float* __restrict__ src,
                                                   float* __restrict__ dst, int K) {
  int idx = blockIdx.x * 256 + threadIdx.x;
  if (idx >= K * 128) return;
  int c = idx & 127, k = idx >> 7;
  dst[idx] = src[c * K + k];
}

__global__ __launch_bounds__(256) void k_count(const int* __restrict__ row, int* __restrict__ cnt) {
  int e = blockIdx.x * 256 + threadIdx.x;
  atomicAdd(&cnt[row[e]], 1);
}

__global__ __launch_bounds__(256) void k_fill(const int* __restrict__ row, int* __restrict__ cursor,
                                              int* __restrict__ elist) {
  int e = blockIdx.x * 256 + threadIdx.x;
  int pos = atomicAdd(&cursor[row[e]], 1);
  elist[pos] = e;
}

// single-block exclusive scan of cnt[0..N) -> start, cursor
__global__ __launch_bounds__(1024) void k_scan(const int* __restrict__ cnt, int* __restrict__ start,
                                               int* __restrict__ cursor, int n) {
  __shared__ int wsum[16];
  __shared__ int carry;
  int tid = threadIdx.x, lane = tid & 63, wid = tid >> 6;
  if (tid == 0) carry = 0;
  __syncthreads();
  for (int base = 0; base < n; base += 1024) {
    int i = base + tid;
    int v = (i < n) ? cnt[i] : 0;
    int x = v;
#pragma unroll
    for (int d = 1; d < 64; d <<= 1) {
      int y = __shfl_up(x, d, 64);
      if (lane >= d) x += y;
    }
    if (lane == 63) wsum[wid] = x;
    __syncthreads();
    if (wid == 0) {
      int s = (lane < 16) ? wsum[lane] : 0;
#pragma unroll
      for (int d = 1; d < 16; d <<= 1) {
        int y = __shfl_up(s, d, 64);
        if (lane >= d) s += y;
      }
      if (lane < 16) wsum[lane] = s;
    }
    __syncthreads();
    int c0 = carry;
    int waveoff = (wid > 0) ? wsum[wid - 1] : 0;
    int incl = c0 + waveoff + x;
    if (i < n) {
      start[i] = incl - v;
      cursor[i] = incl - v;
    }
    __syncthreads();
    if (tid == 1023) carry = incl;
    __syncthreads();
  }
}

// column sums & sumsq of a [R][128] bf16 buffer
__global__ __launch_bounds__(256) void k_stats(const unsigned short* __restrict__ t, int R,
                                               float* __restrict__ gsum, float* __restrict__ gsq) {
  __shared__ float4 sm[256];
  int tid = threadIdx.x;
  int cp = tid & 63;  // channel pair: channels 2cp, 2cp+1
  int rq = tid >> 6;
  float s0 = 0, s1 = 0, q0 = 0, q1 = 0;
  for (int r = blockIdx.x * 4 + rq; r < R; r += gridDim.x * 4) {
    unsigned int u = *(const unsigned int*)(t + (size_t)r * 128 + cp * 2);
    float v0 = bf2f(u & 0xFFFFu), v1 = bf2f(u >> 16);
    s0 += v0; s1 += v1; q0 += v0 * v0; q1 += v1 * v1;
  }
  sm[tid] = make_float4(s0, s1, q0, q1);
  __syncthreads();
  if (tid < 64) {
    float4 a = sm[tid], b = sm[tid + 64], c = sm[tid + 128], d = sm[tid + 192];
    atomicAdd(&gsum[tid * 2 + 0], a.x + b.x + c.x + d.x);
    atomicAdd(&gsum[tid * 2 + 1], a.y + b.y + c.y + d.y);
    atomicAdd(&gsq[tid * 2 + 0], a.z + b.z + c.z + d.z);
    atomicAdd(&gsq[tid * 2 + 1], a.w + b.w + c.w + d.w);
  }
}

__global__ void k_fin(const float* __restrict__ gsum, const float* __restrict__ gsq,
                      const float* __restrict__ g, const float* __restrict__ be, float invR,
                      float* __restrict__ bnS, float* __restrict__ bnSh) {
  int c = threadIdx.x;
  float mean = gsum[c] * invR;
  float var = fmaxf(gsq[c] * invR - mean * mean, 0.f);
  float rs = rsqrtf(var + 1e-5f);
  float s = g[c] * rs;
  bnS[c] = s;
  bnSh[c] = be[c] - mean * s;
}

// ---------------- GEMM kernels (fp32 register-tiled) ----------------
// block: 64 rows x 128 cols, BK=64 chunks; 256 threads, each 4 rows x 8 cols.

#define GEMM_INNER()                                                      \
  _Pragma("unroll 8") for (int k = 0; k < 64; ++k) {                      \
    float a0 = As[ey][k], a1 = As[ey + 16][k];                            \
    float a2 = As[ey + 32][k], a3 = As[ey + 48][k];                       \
    const float4* wv = (const float4*)&Ws[k * 128 + cx * 8];              \
    float4 w0 = wv[0], w1 = wv[1];                                        \
    float wj[8] = {w0.x, w0.y, w0.z, w0.w, w1.x, w1.y, w1.z, w1.w};       \
    _Pragma("unroll") for (int j = 0; j < 8; ++j) {                       \
      acc[0][j] += a0 * wj[j];                                            \
      acc[1][j] += a1 * wj[j];                                            \
      acc[2][j] += a2 * wj[j];                                            \
      acc[3][j] += a3 * wj[j];                                            \
    }                                                                     \
  }

#define STAGE_W()                                                         \
  {                                                                       \
    const float4* wp = (const float4*)(wT + (size_t)k0 * 128);            \
    float4* wd = (float4*)Ws;                                             \
    _Pragma("unroll") for (int u = 0; u < 8; ++u)                         \
        wd[u * 256 + tid] = wp[u * 256 + tid];                            \
  }

// edge layer 1: t1 = [h[row], h[col], radial] @ e_w1^T + b1  (K=256 + radial column)
__global__ __launch_bounds__(256) void k_edge_l1(
    const float* __restrict__ h, const float* __restrict__ coord, const int* __restrict__ row,
    const int* __restrict__ col, const float* __restrict__ wT /*[257][128]*/,
    const float* __restrict__ bias, unsigned short* __restrict__ t) {
  __shared__ float As[64][65];
  __shared__ float Ws[64 * 128];
  __shared__ float rad[64];
  __shared__ int ri[64], ci[64];
  int tid = threadIdx.x;
  long e0 = (long)blockIdx.x * 64;
  if (tid < 64) {
    int e = (int)e0 + tid;
    int r = row[e], c = col[e];
    ri[tid] = r; ci[tid] = c;
    float dx = coord[r * 3 + 0] - coord[c * 3 + 0];
    float dy = coord[r * 3 + 1] - coord[c * 3 + 1];
    float dz = coord[r * 3 + 2] - coord[c * 3 + 2];
    rad[tid] = dx * dx + dy * dy + dz * dz;
  }
  __syncthreads();
  float acc[4][8];
#pragma unroll
  for (int a = 0; a < 4; ++a)
#pragma unroll
    for (int b = 0; b < 8; ++b) acc[a][b] = 0.f;
  int i = tid >> 2, sub = tid & 3;
  int cx = tid & 15, ey = tid >> 4;
  for (int kc = 0; kc < 4; ++kc) {
    int k0 = kc * 64;
    {
      int srow = (k0 < 128) ? ri[i] : ci[i];
      int koff = (k0 & 127) + sub * 16;
      const float4* sp = (const float4*)(h + (size_t)srow * 128 + koff);
      float4 v0 = sp[0], v1 = sp[1], v2 = sp[2], v3 = sp[3];
      float vv[16] = {v0.x, v0.y, v0.z, v0.w, v1.x, v1.y, v1.z, v1.w,
                      v2.x, v2.y, v2.z, v2.w, v3.x, v3.y, v3.z, v3.w};
#pragma unroll
      for (int j = 0; j < 16; ++j) As[i][sub * 16 + j] = vv[j];
    }
    STAGE_W();
    __syncthreads();
    GEMM_INNER();
    __syncthreads();
  }
  const float* wl = wT + 256 * 128 + cx * 8;
  const float* bb = bias + cx * 8;
  float wlv[8], bv[8];
#pragma unroll
  for (int j = 0; j < 8; ++j) { wlv[j] = wl[j]; bv[j] = bb[j]; }
#pragma unroll
  for (int er = 0; er < 4; ++er) {
    int le = ey + er * 16;
    long e = e0 + le;
    float r = rad[le];
    unsigned short us[8];
#pragma unroll
    for (int j = 0; j < 8; ++j) us[j] = f2bf(acc[er][j] + r * wlv[j] + bv[j]);
    uint4 o;
    o.x = (unsigned)us[0] | ((unsigned)us[1] << 16);
    o.y = (unsigned)us[2] | ((unsigned)us[3] << 16);
    o.z = (unsigned)us[4] | ((unsigned)us[5] << 16);
    o.w = (unsigned)us[6] | ((unsigned)us[7] << 16);
    *(uint4*)(t + e * 128 + cx * 8) = o;
  }
}

// generic bf16-in layer: t_out = relu(bn(t_in)) @ wT + bias   (K=128, in-place)
__global__ __launch_bounds__(256) void k_edge_l2(
    unsigned short* __restrict__ t, const float* __restrict__ wT /*[128][128]*/,
    const float* __restrict__ bias, const float* __restrict__ bnS,
    const float* __restrict__ bnSh) {
  __shared__ float As[64][65];
  __shared__ float Ws[64 * 128];
  int tid = threadIdx.x;
  long e0 = (long)blockIdx.x * 64;
  int i = tid >> 2, sub = tid & 3;
  int cx = tid & 15, ey = tid >> 4;
  float acc[4][8];
#pragma unroll
  for (int a = 0; a < 4; ++a)
#pragma unroll
    for (int b = 0; b < 8; ++b) acc[a][b] = 0.f;
  for (int kc = 0; kc < 2; ++kc) {
    int k0 = kc * 64;
    {
      const unsigned short* p = t + (e0 + i) * 128 + k0 + sub * 16;
      uint4 ua = *(const uint4*)p;
      uint4 ub = *(const uint4*)(p + 8);
      unsigned int uu[8] = {ua.x, ua.y, ua.z, ua.w, ub.x, ub.y, ub.z, ub.w};
      int kb = k0 + sub * 16;
#pragma unroll
      for (int j = 0; j < 8; ++j) {
        float lo = bf2f(uu[j] & 0xFFFFu);
        float hi = bf2f(uu[j] >> 16);
        As[i][sub * 16 + 2 * j] = fmaxf(lo * bnS[kb + 2 * j] + bnSh[kb + 2 * j], 0.f);
        As[i][sub * 16 + 2 * j + 1] = fmaxf(hi * bnS[kb + 2 * j + 1] + bnSh[kb + 2 * j + 1], 0.f);
      }
    }
    STAGE_W();
    __syncthreads();
    GEMM_INNER();
    __syncthreads();
  }
  const float* bb = bias + cx * 8;
  float bv[8];
#pragma unroll
  for (int j = 0; j < 8; ++j) bv[j] = bb[j];
#pragma unroll
  for (int er = 0; er < 4; ++er) {
    long e = e0 + ey + er * 16;
    unsigned short us[8];
#pragma unroll
    for (int j = 0; j < 8; ++j) us[j] = f2bf(acc[er][j] + bv[j]);
    uint4 o;
    o.x = (unsigned)us[0] | ((unsigned)us[1] << 16);
    o.y = (unsigned)us[2] | ((unsigned)us[3] << 16);
    o.z = (unsigned)us[4] | ((unsigned)us[5] << 16);
    o.w = (unsigned)us[6] | ((unsigned)us[7] << 16);
    *(uint4*)(t + e * 128 + cx * 8) = o;
  }
}

// node layer 1: t4 = [h, agg] @ n_w1^T + b1  (K=256)
__global__ __launch_bounds__(256) void k_node_l1(
    const float* __restrict__ h, const float* __restrict__ agg,
    const float* __restrict__ wT /*[256][128]*/, const float* __restrict__ bias,
    unsigned short* __restrict__ t) {
  __shared__ float As[64][65];
  __shared__ float Ws[64 * 128];
  int tid = threadIdx.x;
  int n0 = blockIdx.x * 64;
  int i = tid >> 2, sub = tid & 3;
  int cx = tid & 15, ey = tid >> 4;
  int nr = min(n0 + i, Nn - 1);
  float acc[4][8];
#pragma unroll
  for (int a = 0; a < 4; ++a)
#pragma unroll
    for (int b = 0; b < 8; ++b) acc[a][b] = 0.f;
  for (int kc = 0; kc < 4; ++kc) {
    int k0 = kc * 64;
    {
      const float* src = (k0 < 128) ? (h + (size_t)nr * 128 + k0)
                                    : (agg + (size_t)nr * 128 + (k0 - 128));
      const float4* sp = (const float4*)(src + sub * 16);
      float4 v0 = sp[0], v1 = sp[1], v2 = sp[2], v3 = sp[3];
      float vv[16] = {v0.x, v0.y, v0.z, v0.w, v1.x, v1.y, v1.z, v1.w,
                      v2.x, v2.y, v2.z, v2.w, v3.x, v3.y, v3.z, v3.w};
#pragma unroll
      for (int j = 0; j < 16; ++j) As[i][sub * 16 + j] = vv[j];
    }
    STAGE_W();
    __syncthreads();
    GEMM_INNER();
    __syncthreads();
  }
  const float* bb = bias + cx * 8;
#pragma unroll
  for (int er = 0; er < 4; ++er) {
    int node = n0 + ey + er * 16;
    if (node < Nn) {
      unsigned short us[8];
#pragma unroll
      for (int j = 0; j < 8; ++j) us[j] = f2bf(acc[er][j] + bb[j]);
      uint4 o;
      o.x = (unsigned)us[0] | ((unsigned)us[1] << 16);
      o.y = (unsigned)us[2] | ((unsigned)us[3] << 16);
      o.z = (unsigned)us[4] | ((unsigned)us[5] << 16);
      o.w = (unsigned)us[6] | ((unsigned)us[7] << 16);
      *(uint4*)(t + (size_t)node * 128 + cx * 8) = o;
    }
  }
}

// node layer 2: h_out = h + relu(bn(t4)) @ n_w2^T + b2
__global__ __launch_bounds__(256) void k_node_l2(
    const unsigned short* __restrict__ t, const float* __restrict__ h,
    const float* __restrict__ wT, const float* __restrict__ bias,
    const float* __restrict__ bnS, const float* __restrict__ bnSh, float* __restrict__ out) {
  __shared__ float As[64][65];
  __shared__ float Ws[64 * 128];
  int tid = threadIdx.x;
  int n0 = blockIdx.x * 64;
  int i = tid >> 2, sub = tid & 3;
  int cx = tid & 15, ey = tid >> 4;
  int nr = min(n0 + i, Nn - 1);
  float acc[4][8];
#pragma unroll
  for (int a = 0; a < 4; ++a)
#pragma unroll
    for (int b = 0; b < 8; ++b) acc[a][b] = 0.f;
  for (int kc = 0; kc < 2; ++kc) {
    int k0 = kc * 64;
    {
      const unsigned short* p = t + (size_t)nr * 128 + k0 + sub * 16;
      uint4 ua = *(const uint4*)p;
      uint4 ub = *(const uint4*)(p + 8);
      unsigned int uu[8] = {ua.x, ua.y, ua.z, ua.w, ub.x, ub.y, ub.z, ub.w};
      int kb = k0 + sub * 16;
#pragma unroll
      for (int j = 0; j < 8; ++j) {
        float lo = bf2f(uu[j] & 0xFFFFu);
        float hi = bf2f(uu[j] >> 16);
        As[i][sub * 16 + 2 * j] = fmaxf(lo * bnS[kb + 2 * j] + bnSh[kb + 2 * j], 0.f);
        As[i][sub * 16 + 2 * j + 1] = fmaxf(hi * bnS[kb + 2 * j + 1] + bnSh[kb + 2 * j + 1], 0.f);
      }
    }
    STAGE_W();
    __syncthreads();
    GEMM_INNER();
    __syncthreads();
  }
  const float* bb = bias + cx * 8;
#pragma unroll
  for (int er = 0; er < 4; ++er) {
    int node = n0 + ey + er * 16;
    if (node < Nn) {
      const float* hp = h + (size_t)node * 128 + cx * 8;
#pragma unroll
      for (int j = 0; j < 8; ++j)
        out[(size_t)node * 128 + cx * 8 + j] = hp[j] + acc[er][j] + bb[j];
    }
  }
}

// ---------------- per-edge / per-node small kernels ----------------

// scale[e] = relu(bn3(t3[e])) . c_w2   — one wave per edge
__global__ __launch_bounds__(256) void k_scale(const unsigned short* __restrict__ t,
                                               const float* __restrict__ bnS,
                                               const float* __restrict__ bnSh,
                                               const float* __restrict__ cw2,
                                               float* __restrict__ scaleE) {
  int tid = threadIdx.x;
  int lane = tid & 63;
  long e = (long)blockIdx.x * 4 + (tid >> 6);
  int c2 = lane * 2;
  unsigned int u = *(const unsigned int*)(t + e * 128 + c2);
  float v0 = fmaxf(bf2f(u & 0xFFFFu) * bnS[c2] + bnSh[c2], 0.f);
  float v1 = fmaxf(bf2f(u >> 16) * bnS[c2 + 1] + bnSh[c2 + 1], 0.f);
  float p = v0 * cw2[c2] + v1 * cw2[c2 + 1];
#pragma unroll
  for (int d = 32; d; d >>= 1) p += __shfl_xor(p, d, 64);
  if (lane == 0) scaleE[e] = p;
}

// agg[n] = mean over edges(row==n) of relu(bn2(t2[e]))  — one wave per node
__global__ __launch_bounds__(256) void k_agg(const unsigned short* __restrict__ t,
                                             const int* __restrict__ elist,
                                             const int* __restrict__ start,
                                             const int* __restrict__ cnt,
                                             const float* __restrict__ bnS,
                                             const float* __restrict__ bnSh,
                                             float* __restrict__ agg) {
  int tid = threadIdx.x;
  int lane = tid & 63;
  int n = blockIdx.x * 4 + (tid >> 6);
  if (n >= Nn) return;
  int deg = cnt[n], off = start[n];
  int c2 = lane * 2;
  float s0 = bnS[c2], s1 = bnS[c2 + 1], h0 = bnSh[c2], h1 = bnSh[c2 + 1];
  float a0 = 0.f, a1 = 0.f;
  for (int j = 0; j < deg; ++j) {
    int e = elist[off + j];
    unsigned int u = *(const unsigned int*)(t + (size_t)e * 128 + c2);
    a0 += fmaxf(bf2f(u & 0xFFFFu) * s0 + h0, 0.f);
    a1 += fmaxf(bf2f(u >> 16) * s1 + h1, 0.f);
  }
  float inv = 1.f / fmaxf((float)deg, 1.f);
  agg[(size_t)n * 128 + c2] = a0 * inv;
  agg[(size_t)n * 128 + c2 + 1] = a1 * inv;
}

// coord_out[n] = coord[n] + mean over edges of clip((coord[n]-coord[col])*scale, +-100)
__global__ __launch_bounds__(256) void k_coord(const float* __restrict__ coord,
                                               const int* __restrict__ col,
                                               const int* __restrict__ elist,
                                               const int* __restrict__ start,
                                               const int* __restrict__ cnt,
                                               const float* __restrict__ scaleE,
                                               float* __restrict__ cout) {
  int tid = threadIdx.x;
  int lane = tid & 63;
  int n = blockIdx.x * 4 + (tid >> 6);
  if (n >= Nn) return;
  int deg = cnt[n], off = start[n];
  float cx0 = coord[n * 3 + 0], cy0 = coord[n * 3 + 1], cz0 = coord[n * 3 + 2];
  float ax = 0.f, ay = 0.f, az = 0.f;
  for (int j = lane; j < deg; j += 64) {
    int e = elist[off + j];
    int c = col[e];
    float s = scaleE[e];
    float tx = (cx0 - coord[c * 3 + 0]) * s;
    float ty = (cy0 - coord[c * 3 + 1]) * s;
    float tz = (cz0 - coord[c * 3 + 2]) * s;
    ax += fminf(fmaxf(tx, -100.f), 100.f);
    ay += fminf(fmaxf(ty, -100.f), 100.f);
    az += fminf(fmaxf(tz, -100.f), 100.f);
  }
#pragma unroll
  for (int d = 32; d; d >>= 1) {
    ax += __shfl_xor(ax, d, 64);
    ay += __shfl_xor(ay, d, 64);
    az += __shfl_xor(az, d, 64);
  }
  if (lane == 0) {
    float inv = 1.f / fmaxf((float)deg, 1.f);
    cout[n * 3 + 0] = cx0 + ax * inv;
    cout[n * 3 + 1] = cy0 + ay * inv;
    cout[n * 3 + 2] = cz0 + az * inv;
  }
}

// ---------------- launcher ----------------

extern "C" void kernel_launch(void* const* d_in, const int* in_sizes, int n_in, void* d_out,
                              int out_size, void* d_ws, size_t ws_size, hipStream_t stream) {
  (void)in_sizes; (void)n_in; (void)out_size; (void)ws_size;
  const float* h = (const float*)d_in[0];
  const float* coord = (const float*)d_in[1];
  const int* eidx = (const int*)d_in[2];
  const int* row = eidx;
  const int* col = eidx + En;
  const float* e_w1 = (const float*)d_in[3];
  const float* e_b1 = (const float*)d_in[4];
  const float* e_g1 = (const float*)d_in[5];
  const float* e_be1 = (const float*)d_in[6];
  const float* e_w2 = (const float*)d_in[7];
  const float* e_b2 = (const float*)d_in[8];
  const float* e_g2 = (const float*)d_in[9];
  const float* e_be2 = (const float*)d_in[10];
  const float* n_w1 = (const float*)d_in[11];
  const float* n_b1 = (const float*)d_in[12];
  const float* n_g1 = (const float*)d_in[13];
  const float* n_be1 = (const float*)d_in[14];
  const float* n_w2 = (const float*)d_in[15];
  const float* n_b2 = (const float*)d_in[16];
  const float* c_w1 = (const float*)d_in[17];
  const float* c_b1 = (const float*)d_in[18];
  const float* c_g1 = (const float*)d_in[19];
  const float* c_be1 = (const float*)d_in[20];
  const float* c_w2 = (const float*)d_in[21];

  char* base = (char*)d_ws;
  size_t off = 0;
  auto alloc = [&](size_t bytes) -> void* {
    void* p = base + off;
    off = (off + bytes + 255) & ~(size_t)255;
    return p;
  };
  unsigned short* t = (unsigned short*)alloc((size_t)En * 128 * 2);  // 204.8 MB, reused 4x
  float* agg = (float*)alloc((size_t)Nn * 128 * 4);
  float* scaleE = (float*)alloc((size_t)En * 4);
  int* cnt = (int*)alloc((size_t)Nn * 4);
  int* startp = (int*)alloc((size_t)Nn * 4);
  int* cursor = (int*)alloc((size_t)Nn * 4);
  int* elist = (int*)alloc((size_t)En * 4);
  float* gsum = (float*)alloc(4 * 128 * 4);
  float* gsq = (float*)alloc(4 * 128 * 4);
  float* bnS = (float*)alloc(4 * 128 * 4);
  float* bnSh = (float*)alloc(4 * 128 * 4);
  float* w1T = (float*)alloc(257 * 128 * 4);
  float* w2T = (float*)alloc(128 * 128 * 4);
  float* wc1T = (float*)alloc(128 * 128 * 4);
  float* wn1T = (float*)alloc(256 * 128 * 4);
  float* wn2T = (float*)alloc(128 * 128 * 4);

  hipMemsetAsync(cnt, 0, (size_t)Nn * 4, stream);
  hipMemsetAsync(gsum, 0, 4 * 128 * 4, stream);
  hipMemsetAsync(gsq, 0, 4 * 128 * 4, stream);

  k_transpose<<<(257 * 128 + 255) / 256, 256, 0, stream>>>(e_w1, w1T, 257);
  k_transpose<<<(128 * 128 + 255) / 256, 256, 0, stream>>>(e_w2, w2T, 128);
  k_transpose<<<(128 * 128 + 255) / 256, 256, 0, stream>>>(c_w1, wc1T, 128);
  k_transpose<<<(256 * 128 + 255) / 256, 256, 0, stream>>>(n_w1, wn1T, 256);
  k_transpose<<<(128 * 128 + 255) / 256, 256, 0, stream>>>(n_w2, wn2T, 128);

  // CSR build (segment id = row)
  k_count<<<En / 256, 256, 0, stream>>>(row, cnt);
  k_scan<<<1, 1024, 0, stream>>>(cnt, startp, cursor, Nn);
  k_fill<<<En / 256, 256, 0, stream>>>(row, cursor, elist);

  // edge layer 1
  k_edge_l1<<<En / 64, 256, 0, stream>>>(h, coord, row, col, w1T, e_b1, t);
  k_stats<<<1024, 256, 0, stream>>>(t, En, gsum + 0, gsq + 0);
  k_fin<<<1, 128, 0, stream>>>(gsum + 0, gsq + 0, e_g1, e_be1, 1.f / En, bnS + 0, bnSh + 0);

  // edge layer 2
  k_edge_l2<<<En / 64, 256, 0, stream>>>(t, w2T, e_b2, bnS + 0, bnSh + 0);
  k_stats<<<1024, 256, 0, stream>>>(t, En, gsum + 128, gsq + 128);
  k_fin<<<1, 128, 0, stream>>>(gsum + 128, gsq + 128, e_g2, e_be2, 1.f / En, bnS + 128, bnSh + 128);

  // node aggregation of edge_feat = relu(bn2(t2)) (before t is overwritten)
  k_agg<<<(Nn + 3) / 4, 256, 0, stream>>>(t, elist, startp, cnt, bnS + 128, bnSh + 128, agg);

  // coord layer (edge_feat -> t3), in place
  k_edge_l2<<<En / 64, 256, 0, stream>>>(t, wc1T, c_b1, bnS + 128, bnSh + 128);
  k_stats<<<1024, 256, 0, stream>>>(t, En, gsum + 256, gsq + 256);
  k_fin<<<1, 128, 0, stream>>>(gsum + 256, gsq + 256, c_g1, c_be1, 1.f / En, bnS + 256, bnSh + 256);

  // per-edge scalar + coord output
  k_scale<<<En / 4, 256, 0, stream>>>(t, bnS + 256, bnSh + 256, c_w2, scaleE);
  float* hout = (float*)d_out;
  float* cout = hout + (size_t)Nn * 128;
  k_coord<<<(Nn + 3) / 4, 256, 0, stream>>>(coord, col, elist, startp, cnt, scaleE, cout);

  // node MLP (t buffer reused for t4)
  k_node_l1<<<(Nn + 63) / 64, 256, 0, stream>>>(h, agg, wn1T, n_b1, t);
  k_stats<<<1024, 256, 0, stream>>>(t, Nn, gsum + 384, gsq + 384);
  k_fin<<<1, 128, 0, stream>>>(gsum + 384, gsq + 384, n_g1, n_be1, 1.f / Nn, bnS + 384, bnSh + 384);
  k_node_l2<<<(Nn + 63) / 64, 256, 0, stream>>>(t, h, wn2T, n_b2, bnS + 384, bnSh + 384, hout);
}

// Round 2
// 1458.064 us; speedup vs baseline: 1.6292x; 1.6292x over previous
//
#include <hip/hip_runtime.h>

#define Nn 50000
#define En 800000
#define NSLOT 64

typedef __attribute__((ext_vector_type(8))) short short8;
typedef __attribute__((ext_vector_type(4))) float f32x4;

union U8 { uint4 u4; unsigned short us[8]; short8 s8; };

static __device__ __forceinline__ float bf2f(unsigned int lo16) {
  return __uint_as_float(lo16 << 16);
}
static __device__ __forceinline__ unsigned short f2bf(float f) {
  unsigned int x = __float_as_uint(f);
  return (unsigned short)((x + 0x7FFFu + ((x >> 16) & 1u)) >> 16);
}

// ---------------- prep kernels ----------------

// h fp32 [Nn][128] -> nodeA bf16 [Nn][256] cols 0..127
__global__ __launch_bounds__(256) void k_prep_h(const float* __restrict__ h,
                                                unsigned short* __restrict__ nodeA) {
  int idx = blockIdx.x * 256 + threadIdx.x;
  if (idx >= Nn * 128) return;
  int n = idx >> 7, k = idx & 127;
  nodeA[(size_t)n * 256 + k] = f2bf(h[idx]);
}

// weight fp32 [128][Ksrc] -> bf16 [128][1<<kshift] (first 1<<kshift cols)
__global__ __launch_bounds__(256) void k_prep_w(const float* __restrict__ src,
                                                unsigned short* __restrict__ dst, int Ksrc,
                                                int kshift, int total) {
  int idx = blockIdx.x * 256 + threadIdx.x;
  if (idx >= total) return;
  int n = idx >> kshift;
  int k = idx & ((1 << kshift) - 1);
  dst[idx] = f2bf(src[n * Ksrc + k]);
}

__global__ void k_wlast(const float* __restrict__ e_w1, float* __restrict__ wlast) {
  int t = threadIdx.x;
  if (t < 128) wlast[t] = e_w1[t * 257 + 256];
}

// ---------------- CSR build ----------------

__global__ __launch_bounds__(256) void k_count(const int* __restrict__ row, int* __restrict__ cnt) {
  int e = blockIdx.x * 256 + threadIdx.x;
  atomicAdd(&cnt[row[e]], 1);
}

__global__ __launch_bounds__(256) void k_fill(const int* __restrict__ row, int* __restrict__ cursor,
                                              int* __restrict__ elist) {
  int e = blockIdx.x * 256 + threadIdx.x;
  int pos = atomicAdd(&cursor[row[e]], 1);
  elist[pos] = e;
}

__global__ __launch_bounds__(1024) void k_scan(const int* __restrict__ cnt, int* __restrict__ start,
                                               int* __restrict__ cursor, int n) {
  __shared__ int wsum[16];
  __shared__ int carry;
  int tid = threadIdx.x, lane = tid & 63, wid = tid >> 6;
  if (tid == 0) carry = 0;
  __syncthreads();
  for (int base = 0; base < n; base += 1024) {
    int i = base + tid;
    int v = (i < n) ? cnt[i] : 0;
    int x = v;
#pragma unroll
    for (int d = 1; d < 64; d <<= 1) {
      int y = __shfl_up(x, d, 64);
      if (lane >= d) x += y;
    }
    if (lane == 63) wsum[wid] = x;
    __syncthreads();
    if (wid == 0) {
      int s = (lane < 16) ? wsum[lane] : 0;
#pragma unroll
      for (int d = 1; d < 16; d <<= 1) {
        int y = __shfl_up(s, d, 64);
        if (lane >= d) s += y;
      }
      if (lane < 16) wsum[lane] = s;
    }
    __syncthreads();
    int c0 = carry;
    int waveoff = (wid > 0) ? wsum[wid - 1] : 0;
    int incl = c0 + waveoff + x;
    if (i < n) {
      start[i] = incl - v;
      cursor[i] = incl - v;
    }
    __syncthreads();
    if (tid == 1023) carry = incl;
    __syncthreads();
  }
}

// ---------------- BN finalize ----------------

__global__ void k_fin(const float* __restrict__ statS, const float* __restrict__ statQ,
                      const float* __restrict__ g, const float* __restrict__ be, float invR,
                      float* __restrict__ bnS, float* __restrict__ bnSh) {
  int c = threadIdx.x;
  if (c >= 128) return;
  float s = 0.f, q = 0.f;
  for (int k = 0; k < NSLOT; ++k) {
    s += statS[k * 128 + c];
    q += statQ[k * 128 + c];
  }
  float mean = s * invR;
  float var = fmaxf(q * invR - mean * mean, 0.f);
  float rs = rsqrtf(var + 1e-5f);
  float sc = g[c] * rs;
  bnS[c] = sc;
  bnSh[c] = be[c] - mean * sc;
}

// ---------------- MFMA GEMM kernels ----------------
// Tile: 64 rows x 128 cols per block, 4 waves, each wave 16 rows x 128 cols.
// mfma_f32_16x16x32_bf16: A frag A[m=lane&15][k=(lane>>4)*8+j],
//                         B frag B[k=(lane>>4)*8+j][n=lane&15],
//                         C/D:   col=lane&15, row=(lane>>4)*4+reg.
#define TSTR 136  // LDS tile row stride in shorts (17 uint4) — conflict-free epilogue

// edge layer 1: t = [h[row], h[col]] @ e_w1[:, :256]^T + radial*wlast + bias, bf16 out + stats
__global__ __launch_bounds__(256) void k_mfma_l1(
    const unsigned short* __restrict__ hb /* nodeA, stride 256 */,
    const float* __restrict__ coord, const int* __restrict__ rowp, const int* __restrict__ colp,
    const unsigned short* __restrict__ Wb /*[128][256] bf16*/, const float* __restrict__ wlast,
    const float* __restrict__ bias, unsigned short* __restrict__ outb,
    float* __restrict__ statS, float* __restrict__ statQ) {
  __shared__ __align__(16) unsigned short tile[64 * TSTR];
  __shared__ float ssum[4][128], ssq[4][128];
  __shared__ float rad[64];
  int tid = threadIdx.x;
  int w = tid >> 6, lane = tid & 63, m = lane & 15, kq = lane >> 4;
  int rbase = blockIdx.x * 64;
  if (tid < 64) {
    int e = rbase + tid;
    int r = rowp[e], c = colp[e];
    float dx = coord[r * 3 + 0] - coord[c * 3 + 0];
    float dy = coord[r * 3 + 1] - coord[c * 3 + 1];
    float dz = coord[r * 3 + 2] - coord[c * 3 + 2];
    rad[tid] = dx * dx + dy * dy + dz * dz;
  }
  int e = rbase + w * 16 + m;
  int ri = rowp[e], ci = colp[e];
  f32x4 acc[8];
#pragma unroll
  for (int c = 0; c < 8; ++c) acc[c] = (f32x4){0.f, 0.f, 0.f, 0.f};
#pragma unroll 2
  for (int ks = 0; ks < 8; ++ks) {
    int k0 = ks * 32 + kq * 8;
    const unsigned short* ab = hb + (size_t)(k0 < 128 ? ri : ci) * 256 + (k0 & 127);
    U8 ua;
    ua.u4 = *(const uint4*)ab;
#pragma unroll
    for (int c = 0; c < 8; ++c) {
      U8 ub;
      ub.u4 = *(const uint4*)(Wb + (size_t)(c * 16 + m) * 256 + k0);
      acc[c] = __builtin_amdgcn_mfma_f32_16x16x32_bf16(ua.s8, ub.s8, acc[c], 0, 0, 0);
    }
  }
  __syncthreads();  // rad ready
#pragma unroll
  for (int c = 0; c < 8; ++c) {
    int n = c * 16 + m;
    float bn_ = bias[n];
    float wl = wlast[n];
    float s = 0.f, q = 0.f;
#pragma unroll
    for (int j = 0; j < 4; ++j) {
      int rr = w * 16 + kq * 4 + j;
      float v = acc[c][j] + bn_ + rad[rr] * wl;
      tile[rr * TSTR + n] = f2bf(v);
      s += v;
      q = fmaf(v, v, q);
    }
    s += __shfl_xor(s, 16, 64); s += __shfl_xor(s, 32, 64);
    q += __shfl_xor(q, 16, 64); q += __shfl_xor(q, 32, 64);
    if (kq == 0) { ssum[w][n] = s; ssq[w][n] = q; }
  }
  __syncthreads();
  const uint4* tl = (const uint4*)tile;
  size_t obase = (size_t)rbase * 128;
#pragma unroll
  for (int u = 0; u < 4; ++u) {
    int idx = u * 256 + tid;
    int rr = idx >> 4, seg = idx & 15;
    *(uint4*)(outb + obase + (size_t)rr * 128 + seg * 8) = tl[rr * 17 + seg];
  }
  if (tid < 128) {
    float s = ssum[0][tid] + ssum[1][tid] + ssum[2][tid] + ssum[3][tid];
    float q = ssq[0][tid] + ssq[1][tid] + ssq[2][tid] + ssq[3][tid];
    int slot = blockIdx.x & (NSLOT - 1);
    atomicAdd(&statS[slot * 128 + tid], s);
    atomicAdd(&statQ[slot * 128 + tid], q);
  }
}

// generic layer: out = (BN_A ? relu(bn(A)) : A) @ Wb^T + bias
// FP32OUT=false: bf16 out + fused stats.  FP32OUT=true: fp32 out + hres residual.
template <int KSTEPS, bool BN_A, bool FP32OUT>
__global__ __launch_bounds__(256) void k_mfma_gen(
    const unsigned short* __restrict__ A /*[R][KSTEPS*32] bf16*/,
    const unsigned short* __restrict__ Wb /*[128][KSTEPS*32] bf16*/,
    const float* __restrict__ bias, const float* __restrict__ bnS,
    const float* __restrict__ bnSh, unsigned short* __restrict__ outb,
    float* __restrict__ statS, float* __restrict__ statQ, const float* __restrict__ hres,
    float* __restrict__ outf, int R) {
  constexpr int K = KSTEPS * 32;
  int tid = threadIdx.x;
  int w = tid >> 6, lane = tid & 63, m = lane & 15, kq = lane >> 4;
  int rbase = blockIdx.x * 64;
  int row = rbase + w * 16 + m;
  int rowc = min(row, R - 1);
  f32x4 acc[8];
#pragma unroll
  for (int c = 0; c < 8; ++c) acc[c] = (f32x4){0.f, 0.f, 0.f, 0.f};
#pragma unroll 2
  for (int ks = 0; ks < KSTEPS; ++ks) {
    int k0 = ks * 32 + kq * 8;
    U8 ua;
    ua.u4 = *(const uint4*)(A + (size_t)rowc * K + k0);
    if (BN_A) {
      const float4* sp = (const float4*)(bnS + k0);
      const float4* hp = (const float4*)(bnSh + k0);
      float4 s0 = sp[0], s1 = sp[1], h0 = hp[0], h1 = hp[1];
      float sv[8] = {s0.x, s0.y, s0.z, s0.w, s1.x, s1.y, s1.z, s1.w};
      float hv[8] = {h0.x, h0.y, h0.z, h0.w, h1.x, h1.y, h1.z, h1.w};
#pragma unroll
      for (int j = 0; j < 8; ++j) {
        float v = fmaxf(bf2f(ua.us[j]) * sv[j] + hv[j], 0.f);
        ua.us[j] = f2bf(v);
      }
    }
#pragma unroll
    for (int c = 0; c < 8; ++c) {
      U8 ub;
      ub.u4 = *(const uint4*)(Wb + (size_t)(c * 16 + m) * K + k0);
      acc[c] = __builtin_amdgcn_mfma_f32_16x16x32_bf16(ua.s8, ub.s8, acc[c], 0, 0, 0);
    }
  }
  if constexpr (FP32OUT) {
#pragma unroll
    for (int c = 0; c < 8; ++c) {
      int n = c * 16 + m;
      float bn_ = bias[n];
#pragma unroll
      for (int j = 0; j < 4; ++j) {
        int rr = rbase + w * 16 + kq * 4 + j;
        if (rr < R) {
          size_t o = (size_t)rr * 128 + n;
          outf[o] = acc[c][j] + bn_ + hres[o];
        }
      }
    }
  } else {
    __shared__ __align__(16) unsigned short tile[64 * TSTR];
    __shared__ float ssum[4][128], ssq[4][128];
#pragma unroll
    for (int c = 0; c < 8; ++c) {
      int n = c * 16 + m;
      float bn_ = bias[n];
      float s = 0.f, q = 0.f;
#pragma unroll
      for (int j = 0; j < 4; ++j) {
        int rr = w * 16 + kq * 4 + j;
        float v = acc[c][j] + bn_;
        tile[rr * TSTR + n] = f2bf(v);
        bool valid = (rbase + rr) < R;
        float sv = valid ? v : 0.f;
        s += sv;
        q = fmaf(sv, sv, q);
      }
      s += __shfl_xor(s, 16, 64); s += __shfl_xor(s, 32, 64);
      q += __shfl_xor(q, 16, 64); q += __shfl_xor(q, 32, 64);
      if (kq == 0) { ssum[w][n] = s; ssq[w][n] = q; }
    }
    __syncthreads();
    const uint4* tl = (const uint4*)tile;
#pragma unroll
    for (int u = 0; u < 4; ++u) {
      int idx = u * 256 + tid;
      int rr = idx >> 4, seg = idx & 15;
      if (rbase + rr < R)
        *(uint4*)(outb + (size_t)(rbase + rr) * 128 + seg * 8) = tl[rr * 17 + seg];
    }
    if (tid < 128) {
      float s = ssum[0][tid] + ssum[1][tid] + ssum[2][tid] + ssum[3][tid];
      float q = ssq[0][tid] + ssq[1][tid] + ssq[2][tid] + ssq[3][tid];
      int slot = blockIdx.x & (NSLOT - 1);
      atomicAdd(&statS[slot * 128 + tid], s);
      atomicAdd(&statQ[slot * 128 + tid], q);
    }
  }
}

// ---------------- per-edge / per-node small kernels ----------------

// scale[e] = relu(bn3(t3[e])) . c_w2   — one wave per edge
__global__ __launch_bounds__(256) void k_scale(const unsigned short* __restrict__ t,
                                               const float* __restrict__ bnS,
                                               const float* __restrict__ bnSh,
                                               const float* __restrict__ cw2,
                                               float* __restrict__ scaleE) {
  int tid = threadIdx.x;
  int lane = tid & 63;
  long e = (long)blockIdx.x * 4 + (tid >> 6);
  int c2 = lane * 2;
  unsigned int u = *(const unsigned int*)(t + e * 128 + c2);
  float v0 = fmaxf(bf2f(u & 0xFFFFu) * bnS[c2] + bnSh[c2], 0.f);
  float v1 = fmaxf(bf2f(u >> 16) * bnS[c2 + 1] + bnSh[c2 + 1], 0.f);
  float p = v0 * cw2[c2] + v1 * cw2[c2 + 1];
#pragma unroll
  for (int d = 32; d; d >>= 1) p += __shfl_xor(p, d, 64);
  if (lane == 0) scaleE[e] = p;
}

// agg (mean of relu(bn2(t2)) over edges of node) -> nodeA[:,128:256] bf16
__global__ __launch_bounds__(256) void k_agg(const unsigned short* __restrict__ t,
                                             const int* __restrict__ elist,
                                             const int* __restrict__ start,
                                             const int* __restrict__ cnt,
                                             const float* __restrict__ bnS,
                                             const float* __restrict__ bnSh,
                                             unsigned short* __restrict__ nodeA) {
  int tid = threadIdx.x;
  int lane = tid & 63;
  int n = blockIdx.x * 4 + (tid >> 6);
  if (n >= Nn) return;
  int deg = cnt[n], off = start[n];
  int c2 = lane * 2;
  float s0 = bnS[c2], s1 = bnS[c2 + 1], h0 = bnSh[c2], h1 = bnSh[c2 + 1];
  float a0 = 0.f, a1 = 0.f;
  for (int j = 0; j < deg; ++j) {
    int e = elist[off + j];
    unsigned int u = *(const unsigned int*)(t + (size_t)e * 128 + c2);
    a0 += fmaxf(bf2f(u & 0xFFFFu) * s0 + h0, 0.f);
    a1 += fmaxf(bf2f(u >> 16) * s1 + h1, 0.f);
  }
  float inv = 1.f / fmaxf((float)deg, 1.f);
  unsigned int o = (unsigned)f2bf(a0 * inv) | ((unsigned)f2bf(a1 * inv) << 16);
  *(unsigned int*)(nodeA + (size_t)n * 256 + 128 + c2) = o;
}

// coord_out[n] = coord[n] + mean over edges of clip((coord[n]-coord[col])*scale, +-100)
__global__ __launch_bounds__(256) void k_coord(const float* __restrict__ coord,
                                               const int* __restrict__ col,
                                               const int* __restrict__ elist,
                                               const int* __restrict__ start,
                                               const int* __restrict__ cnt,
                                               const float* __restrict__ scaleE,
                                               float* __restrict__ cout) {
  int tid = threadIdx.x;
  int lane = tid & 63;
  int n = blockIdx.x * 4 + (tid >> 6);
  if (n >= Nn) return;
  int deg = cnt[n], off = start[n];
  float cx0 = coord[n * 3 + 0], cy0 = coord[n * 3 + 1], cz0 = coord[n * 3 + 2];
  float ax = 0.f, ay = 0.f, az = 0.f;
  for (int j = lane; j < deg; j += 64) {
    int e = elist[off + j];
    int c = col[e];
    float s = scaleE[e];
    float tx = (cx0 - coord[c * 3 + 0]) * s;
    float ty = (cy0 - coord[c * 3 + 1]) * s;
    float tz = (cz0 - coord[c * 3 + 2]) * s;
    ax += fminf(fmaxf(tx, -100.f), 100.f);
    ay += fminf(fmaxf(ty, -100.f), 100.f);
    az += fminf(fmaxf(tz, -100.f), 100.f);
  }
#pragma unroll
  for (int d = 32; d; d >>= 1) {
    ax += __shfl_xor(ax, d, 64);
    ay += __shfl_xor(ay, d, 64);
    az += __shfl_xor(az, d, 64);
  }
  if (lane == 0) {
    float inv = 1.f / fmaxf((float)deg, 1.f);
    cout[n * 3 + 0] = cx0 + ax * inv;
    cout[n * 3 + 1] = cy0 + ay * inv;
    cout[n * 3 + 2] = cz0 + az * inv;
  }
}

// ---------------- launcher ----------------

extern "C" void kernel_launch(void* const* d_in, const int* in_sizes, int n_in, void* d_out,
                              int out_size, void* d_ws, size_t ws_size, hipStream_t stream) {
  (void)in_sizes; (void)n_in; (void)out_size; (void)ws_size;
  const float* h = (const float*)d_in[0];
  const float* coord = (const float*)d_in[1];
  const int* eidx = (const int*)d_in[2];
  const int* row = eidx;
  const int* col = eidx + En;
  const float* e_w1 = (const float*)d_in[3];
  const float* e_b1 = (const float*)d_in[4];
  const float* e_g1 = (const float*)d_in[5];
  const float* e_be1 = (const float*)d_in[6];
  const float* e_w2 = (const float*)d_in[7];
  const float* e_b2 = (const float*)d_in[8];
  const float* e_g2 = (const float*)d_in[9];
  const float* e_be2 = (const float*)d_in[10];
  const float* n_w1 = (const float*)d_in[11];
  const float* n_b1 = (const float*)d_in[12];
  const float* n_g1 = (const float*)d_in[13];
  const float* n_be1 = (const float*)d_in[14];
  const float* n_w2 = (const float*)d_in[15];
  const float* n_b2 = (const float*)d_in[16];
  const float* c_w1 = (const float*)d_in[17];
  const float* c_b1 = (const float*)d_in[18];
  const float* c_g1 = (const float*)d_in[19];
  const float* c_be1 = (const float*)d_in[20];
  const float* c_w2 = (const float*)d_in[21];

  char* base = (char*)d_ws;
  size_t off = 0;
  auto alloc = [&](size_t bytes) -> void* {
    void* p = base + off;
    off = (off + bytes + 255) & ~(size_t)255;
    return p;
  };
  unsigned short* t = (unsigned short*)alloc((size_t)En * 128 * 2);     // 204.8 MB
  unsigned short* nodeA = (unsigned short*)alloc((size_t)Nn * 256 * 2); // 25.6 MB [h | agg] bf16
  float* scaleE = (float*)alloc((size_t)En * 4);
  int* cnt = (int*)alloc((size_t)Nn * 4);
  int* startp = (int*)alloc((size_t)Nn * 4);
  int* cursor = (int*)alloc((size_t)Nn * 4);
  int* elist = (int*)alloc((size_t)En * 4);
  float* statS = (float*)alloc(4 * NSLOT * 128 * 4);
  float* statQ = (float*)alloc(4 * NSLOT * 128 * 4);
  float* bnS = (float*)alloc(4 * 128 * 4);
  float* bnSh = (float*)alloc(4 * 128 * 4);
  unsigned short* w1b = (unsigned short*)alloc(128 * 256 * 2);
  unsigned short* w2b = (unsigned short*)alloc(128 * 128 * 2);
  unsigned short* c1b = (unsigned short*)alloc(128 * 128 * 2);
  unsigned short* n1b = (unsigned short*)alloc(128 * 256 * 2);
  unsigned short* n2b = (unsigned short*)alloc(128 * 128 * 2);
  float* wlast = (float*)alloc(128 * 4);

  hipMemsetAsync(cnt, 0, (size_t)Nn * 4, stream);
  hipMemsetAsync(statS, 0, 4 * NSLOT * 128 * 4, stream);
  hipMemsetAsync(statQ, 0, 4 * NSLOT * 128 * 4, stream);

  // prep: bf16 h + weights
  k_prep_h<<<(Nn * 128 + 255) / 256, 256, 0, stream>>>(h, nodeA);
  k_prep_w<<<(128 * 256 + 255) / 256, 256, 0, stream>>>(e_w1, w1b, 257, 8, 128 * 256);
  k_prep_w<<<(128 * 128 + 255) / 256, 256, 0, stream>>>(e_w2, w2b, 128, 7, 128 * 128);
  k_prep_w<<<(128 * 128 + 255) / 256, 256, 0, stream>>>(c_w1, c1b, 128, 7, 128 * 128);
  k_prep_w<<<(128 * 256 + 255) / 256, 256, 0, stream>>>(n_w1, n1b, 256, 8, 128 * 256);
  k_prep_w<<<(128 * 128 + 255) / 256, 256, 0, stream>>>(n_w2, n2b, 128, 7, 128 * 128);
  k_wlast<<<1, 128, 0, stream>>>(e_w1, wlast);

  // CSR build (segment id = row)
  k_count<<<En / 256, 256, 0, stream>>>(row, cnt);
  k_scan<<<1, 1024, 0, stream>>>(cnt, startp, cursor, Nn);
  k_fill<<<En / 256, 256, 0, stream>>>(row, cursor, elist);

  // edge layer 1 (gather MFMA, fused stats -> layer 0)
  k_mfma_l1<<<En / 64, 256, 0, stream>>>(nodeA, coord, row, col, w1b, wlast, e_b1, t,
                                         statS + 0 * NSLOT * 128, statQ + 0 * NSLOT * 128);
  k_fin<<<1, 128, 0, stream>>>(statS + 0 * NSLOT * 128, statQ + 0 * NSLOT * 128, e_g1, e_be1,
                               1.f / En, bnS + 0, bnSh + 0);

  // edge layer 2 (in-place on t, stats -> layer 1)
  k_mfma_gen<4, true, false><<<En / 64, 256, 0, stream>>>(
      t, w2b, e_b2, bnS + 0, bnSh + 0, t, statS + 1 * NSLOT * 128, statQ + 1 * NSLOT * 128,
      nullptr, nullptr, En);
  k_fin<<<1, 128, 0, stream>>>(statS + 1 * NSLOT * 128, statQ + 1 * NSLOT * 128, e_g2, e_be2,
                               1.f / En, bnS + 128, bnSh + 128);

  // node aggregation of edge_feat = relu(bn2(t2)) -> nodeA[:,128:]
  k_agg<<<(Nn + 3) / 4, 256, 0, stream>>>(t, elist, startp, cnt, bnS + 128, bnSh + 128, nodeA);

  // coord layer 1 (in-place on t, stats -> layer 2)
  k_mfma_gen<4, true, false><<<En / 64, 256, 0, stream>>>(
      t, c1b, c_b1, bnS + 128, bnSh + 128, t, statS + 2 * NSLOT * 128, statQ + 2 * NSLOT * 128,
      nullptr, nullptr, En);
  k_fin<<<1, 128, 0, stream>>>(statS + 2 * NSLOT * 128, statQ + 2 * NSLOT * 128, c_g1, c_be1,
                               1.f / En, bnS + 256, bnSh + 256);

  // per-edge scalar + coord output
  k_scale<<<En / 4, 256, 0, stream>>>(t, bnS + 256, bnSh + 256, c_w2, scaleE);
  float* hout = (float*)d_out;
  float* cout = hout + (size_t)Nn * 128;
  k_coord<<<(Nn + 3) / 4, 256, 0, stream>>>(coord, col, elist, startp, cnt, scaleE, cout);

  // node MLP: l1 = [h|agg] @ n_w1^T + b1 (stats -> layer 3), l2 = residual fp32 out
  k_mfma_gen<8, false, false><<<(Nn + 63) / 64, 256, 0, stream>>>(
      nodeA, n1b, n_b1, nullptr, nullptr, t, statS + 3 * NSLOT * 128, statQ + 3 * NSLOT * 128,
      nullptr, nullptr, Nn);
  k_fin<<<1, 128, 0, stream>>>(statS + 3 * NSLOT * 128, statQ + 3 * NSLOT * 128, n_g1, n_be1,
                               1.f / Nn, bnS + 384, bnSh + 384);
  k_mfma_gen<4, true, true><<<(Nn + 63) / 64, 256, 0, stream>>>(
      t, n2b, n_b2, bnS + 384, bnSh + 384, nullptr, nullptr, nullptr, h, hout, Nn);
}

// Round 3
// 897.008 us; speedup vs baseline: 2.6482x; 1.6255x over previous
//
#include <hip/hip_runtime.h>

#define Nn 50000
#define En 800000
#define NSLOT 64

typedef __attribute__((ext_vector_type(8))) short short8;
typedef __attribute__((ext_vector_type(4))) float f32x4;

union U8 { uint4 u4; unsigned short us[8]; short8 s8; };

static __device__ __forceinline__ float bf2f(unsigned int lo16) {
  return __uint_as_float(lo16 << 16);
}
static __device__ __forceinline__ unsigned short f2bf(float f) {
  unsigned int x = __float_as_uint(f);
  return (unsigned short)((x + 0x7FFFu + ((x >> 16) & 1u)) >> 16);
}

// ---------------- prep kernels ----------------

// h fp32 [Nn][128] -> nodeA bf16 [Nn][256] cols 0..127
__global__ __launch_bounds__(256) void k_prep_h(const float* __restrict__ h,
                                                unsigned short* __restrict__ nodeA) {
  int idx = blockIdx.x * 256 + threadIdx.x;
  if (idx >= Nn * 128) return;
  int n = idx >> 7, k = idx & 127;
  nodeA[(size_t)n * 256 + k] = f2bf(h[idx]);
}

// weight fp32 [128][Ksrc] cols [koff, koff+2^kshift) -> bf16 [128][2^kshift]
__global__ __launch_bounds__(256) void k_prep_w(const float* __restrict__ src,
                                                unsigned short* __restrict__ dst, int Ksrc,
                                                int koff, int kshift, int total) {
  int idx = blockIdx.x * 256 + threadIdx.x;
  if (idx >= total) return;
  int n = idx >> kshift;
  int k = idx & ((1 << kshift) - 1);
  dst[idx] = f2bf(src[n * Ksrc + koff + k]);
}

__global__ void k_wlast(const float* __restrict__ e_w1, float* __restrict__ wlast) {
  int t = threadIdx.x;
  if (t < 128) wlast[t] = e_w1[t * 257 + 256];
}

// ---------------- CSR build ----------------

__global__ __launch_bounds__(256) void k_count(const int* __restrict__ row, int* __restrict__ cnt) {
  int e = blockIdx.x * 256 + threadIdx.x;
  atomicAdd(&cnt[row[e]], 1);
}

__global__ __launch_bounds__(256) void k_fill(const int* __restrict__ row, int* __restrict__ cursor,
                                              int* __restrict__ elist) {
  int e = blockIdx.x * 256 + threadIdx.x;
  int pos = atomicAdd(&cursor[row[e]], 1);
  elist[pos] = e;
}

__global__ __launch_bounds__(1024) void k_scan(const int* __restrict__ cnt, int* __restrict__ start,
                                               int* __restrict__ cursor, int n) {
  __shared__ int wsum[16];
  __shared__ int carry;
  int tid = threadIdx.x, lane = tid & 63, wid = tid >> 6;
  if (tid == 0) carry = 0;
  __syncthreads();
  for (int base = 0; base < n; base += 1024) {
    int i = base + tid;
    int v = (i < n) ? cnt[i] : 0;
    int x = v;
#pragma unroll
    for (int d = 1; d < 64; d <<= 1) {
      int y = __shfl_up(x, d, 64);
      if (lane >= d) x += y;
    }
    if (lane == 63) wsum[wid] = x;
    __syncthreads();
    if (wid == 0) {
      int s = (lane < 16) ? wsum[lane] : 0;
#pragma unroll
      for (int d = 1; d < 16; d <<= 1) {
        int y = __shfl_up(s, d, 64);
        if (lane >= d) s += y;
      }
      if (lane < 16) wsum[lane] = s;
    }
    __syncthreads();
    int c0 = carry;
    int waveoff = (wid > 0) ? wsum[wid - 1] : 0;
    int incl = c0 + waveoff + x;
    if (i < n) {
      start[i] = incl - v;
      cursor[i] = incl - v;
    }
    __syncthreads();
    if (tid == 1023) carry = incl;
    __syncthreads();
  }
}

// ---------------- BN finalize ----------------

__global__ void k_fin(const float* __restrict__ statS, const float* __restrict__ statQ,
                      const float* __restrict__ g, const float* __restrict__ be, float invR,
                      float* __restrict__ bnS, float* __restrict__ bnSh) {
  int c = threadIdx.x;
  if (c >= 128) return;
  float s = 0.f, q = 0.f;
  for (int k = 0; k < NSLOT; ++k) {
    s += statS[k * 128 + c];
    q += statQ[k * 128 + c];
  }
  float mean = s * invR;
  float var = fmaxf(q * invR - mean * mean, 0.f);
  float rs = rsqrtf(var + 1e-5f);
  float sc = g[c] * rs;
  bnS[c] = sc;
  bnSh[c] = be[c] - mean * sc;
}

// ---------------- MFMA GEMM with W staged in LDS ----------------
// Block: 128 rows x 128 cols, 4 waves; wave w covers rows [w*32, w*32+32) as 2 row-tiles.
// W [128][K] bf16 staged to LDS with row stride K+8 (bank-group-uniform ds_read_b128).
// LDS buffer reused as the epilogue transpose tile (stride 136).
template <int KSTEPS, bool BN_A, bool STATS, bool FP32OUT>
__global__ __launch_bounds__(256) void k_gemmW(
    const unsigned short* __restrict__ A, int Astride /*shorts*/,
    const unsigned short* __restrict__ W /*[128][K] bf16*/, const float* __restrict__ bias,
    const float* __restrict__ bnS, const float* __restrict__ bnSh,
    unsigned short* __restrict__ outb, float* __restrict__ statS, float* __restrict__ statQ,
    const float* __restrict__ hres, float* __restrict__ outf, int R) {
  constexpr int K = KSTEPS * 32;
  constexpr int WST = K + 8;   // LDS W row stride in shorts
  constexpr int SEGS = K / 8;  // 16B segments per W row
  __shared__ __align__(16) unsigned short smem[128 * WST];
  __shared__ float ssum[4][128], ssq[4][128];
  int tid = threadIdx.x;
  int w = tid >> 6, lane = tid & 63, m = lane & 15, kq = lane >> 4;
  int rbase = blockIdx.x * 128;
  // stage W -> LDS (coalesced)
#pragma unroll
  for (int it = 0; it < SEGS / 2; ++it) {
    int idx = it * 256 + tid;
    int n = idx / SEGS, seg = idx % SEGS;
    uint4 v = *(const uint4*)(W + (size_t)n * K + seg * 8);
    *(uint4*)(smem + n * WST + seg * 8) = v;
  }
  __syncthreads();
  int row0 = rbase + w * 32 + m;
  int rc0 = min(row0, R - 1);
  int rc1 = min(row0 + 16, R - 1);
  f32x4 acc[2][8];
#pragma unroll
  for (int rt = 0; rt < 2; ++rt)
#pragma unroll
    for (int c = 0; c < 8; ++c) acc[rt][c] = (f32x4){0.f, 0.f, 0.f, 0.f};
#pragma unroll
  for (int ks = 0; ks < KSTEPS; ++ks) {
    int k0 = ks * 32 + kq * 8;
    U8 ua0, ua1;
    ua0.u4 = *(const uint4*)(A + (size_t)rc0 * Astride + k0);
    ua1.u4 = *(const uint4*)(A + (size_t)rc1 * Astride + k0);
    if (BN_A) {
      const float4* sp = (const float4*)(bnS + k0);
      const float4* hp = (const float4*)(bnSh + k0);
      float4 s0 = sp[0], s1 = sp[1], h0 = hp[0], h1 = hp[1];
      float sv[8] = {s0.x, s0.y, s0.z, s0.w, s1.x, s1.y, s1.z, s1.w};
      float hv[8] = {h0.x, h0.y, h0.z, h0.w, h1.x, h1.y, h1.z, h1.w};
#pragma unroll
      for (int j = 0; j < 8; ++j) {
        ua0.us[j] = f2bf(fmaxf(bf2f(ua0.us[j]) * sv[j] + hv[j], 0.f));
        ua1.us[j] = f2bf(fmaxf(bf2f(ua1.us[j]) * sv[j] + hv[j], 0.f));
      }
    }
#pragma unroll
    for (int c = 0; c < 8; ++c) {
      U8 ub;
      ub.u4 = *(const uint4*)(smem + (c * 16 + m) * WST + k0);
      acc[0][c] = __builtin_amdgcn_mfma_f32_16x16x32_bf16(ua0.s8, ub.s8, acc[0][c], 0, 0, 0);
      acc[1][c] = __builtin_amdgcn_mfma_f32_16x16x32_bf16(ua1.s8, ub.s8, acc[1][c], 0, 0, 0);
    }
  }
  if constexpr (FP32OUT) {
#pragma unroll
    for (int rt = 0; rt < 2; ++rt)
#pragma unroll
      for (int c = 0; c < 8; ++c) {
        int n = c * 16 + m;
        float bn_ = bias[n];
#pragma unroll
        for (int j = 0; j < 4; ++j) {
          int rr = rbase + w * 32 + rt * 16 + kq * 4 + j;
          if (rr < R) {
            size_t o = (size_t)rr * 128 + n;
            outf[o] = acc[rt][c][j] + bn_ + hres[o];
          }
        }
      }
  } else {
    __syncthreads();  // all waves done reading W before tile overwrite
    unsigned short* tile = smem;  // [128][136]
#pragma unroll
    for (int c = 0; c < 8; ++c) {
      int n = c * 16 + m;
      float bn_ = bias ? bias[n] : 0.f;
      float s = 0.f, q = 0.f;
#pragma unroll
      for (int rt = 0; rt < 2; ++rt)
#pragma unroll
        for (int j = 0; j < 4; ++j) {
          int lr = w * 32 + rt * 16 + kq * 4 + j;
          float v = acc[rt][c][j] + bn_;
          tile[lr * 136 + n] = f2bf(v);
          if (STATS) {
            float sv = (rbase + lr < R) ? v : 0.f;
            s += sv;
            q = fmaf(sv, sv, q);
          }
        }
      if (STATS) {
        s += __shfl_xor(s, 16, 64); s += __shfl_xor(s, 32, 64);
        q += __shfl_xor(q, 16, 64); q += __shfl_xor(q, 32, 64);
        if (kq == 0) { ssum[w][n] = s; ssq[w][n] = q; }
      }
    }
    __syncthreads();
    const uint4* tl = (const uint4*)tile;
#pragma unroll
    for (int u = 0; u < 8; ++u) {
      int idx = u * 256 + tid;
      int rr = idx >> 4, seg = idx & 15;
      if (rbase + rr < R)
        *(uint4*)(outb + (size_t)(rbase + rr) * 128 + seg * 8) = tl[rr * 17 + seg];
    }
    if (STATS && tid < 128) {
      float s = ssum[0][tid] + ssum[1][tid] + ssum[2][tid] + ssum[3][tid];
      float q = ssq[0][tid] + ssq[1][tid] + ssq[2][tid] + ssq[3][tid];
      int slot = blockIdx.x & (NSLOT - 1);
      atomicAdd(&statS[slot * 128 + tid], s);
      atomicAdd(&statQ[slot * 128 + tid], q);
    }
  }
}

// ---------------- edge layer 1 combine (factorized) ----------------
// t1[e] = hWr[row[e]] + hWc[col[e]] + radial[e]*wlast   (+bias folded into hWr)
__global__ __launch_bounds__(256) void k_edge_comb(
    const unsigned short* __restrict__ hWr, const unsigned short* __restrict__ hWc,
    const float* __restrict__ coord, const int* __restrict__ rowp, const int* __restrict__ colp,
    const float* __restrict__ wlast, unsigned short* __restrict__ t,
    float* __restrict__ statS, float* __restrict__ statQ, int nwaves) {
  int tid = threadIdx.x, lane = tid & 63;
  int wid = blockIdx.x * 4 + (tid >> 6);
  int c2 = lane * 2;
  float wl0 = wlast[c2], wl1 = wlast[c2 + 1];
  float s0 = 0.f, s1 = 0.f, q0 = 0.f, q1 = 0.f;
  for (int e = wid; e < En; e += nwaves) {
    int r = rowp[e], c = colp[e];
    float dx = coord[r * 3 + 0] - coord[c * 3 + 0];
    float dy = coord[r * 3 + 1] - coord[c * 3 + 1];
    float dz = coord[r * 3 + 2] - coord[c * 3 + 2];
    float rad = dx * dx + dy * dy + dz * dz;
    unsigned int ua = *(const unsigned int*)(hWr + (size_t)r * 128 + c2);
    unsigned int ub = *(const unsigned int*)(hWc + (size_t)c * 128 + c2);
    float v0 = bf2f(ua & 0xFFFFu) + bf2f(ub & 0xFFFFu) + rad * wl0;
    float v1 = bf2f(ua >> 16) + bf2f(ub >> 16) + rad * wl1;
    *(unsigned int*)(t + (size_t)e * 128 + c2) = (unsigned)f2bf(v0) | ((unsigned)f2bf(v1) << 16);
    s0 += v0; q0 = fmaf(v0, v0, q0);
    s1 += v1; q1 = fmaf(v1, v1, q1);
  }
  int slot = wid & (NSLOT - 1);
  atomicAdd(&statS[slot * 128 + c2], s0);
  atomicAdd(&statS[slot * 128 + c2 + 1], s1);
  atomicAdd(&statQ[slot * 128 + c2], q0);
  atomicAdd(&statQ[slot * 128 + c2 + 1], q1);
}

// ---------------- per-edge / per-node small kernels ----------------

__global__ __launch_bounds__(256) void k_scale(const unsigned short* __restrict__ t,
                                               const float* __restrict__ bnS,
                                               const float* __restrict__ bnSh,
                                               const float* __restrict__ cw2,
                                               float* __restrict__ scaleE) {
  int tid = threadIdx.x;
  int lane = tid & 63;
  long e = (long)blockIdx.x * 4 + (tid >> 6);
  int c2 = lane * 2;
  unsigned int u = *(const unsigned int*)(t + e * 128 + c2);
  float v0 = fmaxf(bf2f(u & 0xFFFFu) * bnS[c2] + bnSh[c2], 0.f);
  float v1 = fmaxf(bf2f(u >> 16) * bnS[c2 + 1] + bnSh[c2 + 1], 0.f);
  float p = v0 * cw2[c2] + v1 * cw2[c2 + 1];
#pragma unroll
  for (int d = 32; d; d >>= 1) p += __shfl_xor(p, d, 64);
  if (lane == 0) scaleE[e] = p;
}

__global__ __launch_bounds__(256) void k_agg(const unsigned short* __restrict__ t,
                                             const int* __restrict__ elist,
                                             const int* __restrict__ start,
                                             const int* __restrict__ cnt,
                                             const float* __restrict__ bnS,
                                             const float* __restrict__ bnSh,
                                             unsigned short* __restrict__ nodeA) {
  int tid = threadIdx.x;
  int lane = tid & 63;
  int n = blockIdx.x * 4 + (tid >> 6);
  if (n >= Nn) return;
  int deg = cnt[n], off = start[n];
  int c2 = lane * 2;
  float s0 = bnS[c2], s1 = bnS[c2 + 1], h0 = bnSh[c2], h1 = bnSh[c2 + 1];
  float a0 = 0.f, a1 = 0.f;
  for (int j = 0; j < deg; ++j) {
    int e = elist[off + j];
    unsigned int u = *(const unsigned int*)(t + (size_t)e * 128 + c2);
    a0 += fmaxf(bf2f(u & 0xFFFFu) * s0 + h0, 0.f);
    a1 += fmaxf(bf2f(u >> 16) * s1 + h1, 0.f);
  }
  float inv = 1.f / fmaxf((float)deg, 1.f);
  unsigned int o = (unsigned)f2bf(a0 * inv) | ((unsigned)f2bf(a1 * inv) << 16);
  *(unsigned int*)(nodeA + (size_t)n * 256 + 128 + c2) = o;
}

__global__ __launch_bounds__(256) void k_coord(const float* __restrict__ coord,
                                               const int* __restrict__ col,
                                               const int* __restrict__ elist,
                                               const int* __restrict__ start,
                                               const int* __restrict__ cnt,
                                               const float* __restrict__ scaleE,
                                               float* __restrict__ cout) {
  int tid = threadIdx.x;
  int lane = tid & 63;
  int n = blockIdx.x * 4 + (tid >> 6);
  if (n >= Nn) return;
  int deg = cnt[n], off = start[n];
  float cx0 = coord[n * 3 + 0], cy0 = coord[n * 3 + 1], cz0 = coord[n * 3 + 2];
  float ax = 0.f, ay = 0.f, az = 0.f;
  for (int j = lane; j < deg; j += 64) {
    int e = elist[off + j];
    int c = col[e];
    float s = scaleE[e];
    float tx = (cx0 - coord[c * 3 + 0]) * s;
    float ty = (cy0 - coord[c * 3 + 1]) * s;
    float tz = (cz0 - coord[c * 3 + 2]) * s;
    ax += fminf(fmaxf(tx, -100.f), 100.f);
    ay += fminf(fmaxf(ty, -100.f), 100.f);
    az += fminf(fmaxf(tz, -100.f), 100.f);
  }
#pragma unroll
  for (int d = 32; d; d >>= 1) {
    ax += __shfl_xor(ax, d, 64);
    ay += __shfl_xor(ay, d, 64);
    az += __shfl_xor(az, d, 64);
  }
  if (lane == 0) {
    float inv = 1.f / fmaxf((float)deg, 1.f);
    cout[n * 3 + 0] = cx0 + ax * inv;
    cout[n * 3 + 1] = cy0 + ay * inv;
    cout[n * 3 + 2] = cz0 + az * inv;
  }
}

// ---------------- launcher ----------------

extern "C" void kernel_launch(void* const* d_in, const int* in_sizes, int n_in, void* d_out,
                              int out_size, void* d_ws, size_t ws_size, hipStream_t stream) {
  (void)in_sizes; (void)n_in; (void)out_size; (void)ws_size;
  const float* h = (const float*)d_in[0];
  const float* coord = (const float*)d_in[1];
  const int* eidx = (const int*)d_in[2];
  const int* row = eidx;
  const int* col = eidx + En;
  const float* e_w1 = (const float*)d_in[3];
  const float* e_b1 = (const float*)d_in[4];
  const float* e_g1 = (const float*)d_in[5];
  const float* e_be1 = (const float*)d_in[6];
  const float* e_w2 = (const float*)d_in[7];
  const float* e_b2 = (const float*)d_in[8];
  const float* e_g2 = (const float*)d_in[9];
  const float* e_be2 = (const float*)d_in[10];
  const float* n_w1 = (const float*)d_in[11];
  const float* n_b1 = (const float*)d_in[12];
  const float* n_g1 = (const float*)d_in[13];
  const float* n_be1 = (const float*)d_in[14];
  const float* n_w2 = (const float*)d_in[15];
  const float* n_b2 = (const float*)d_in[16];
  const float* c_w1 = (const float*)d_in[17];
  const float* c_b1 = (const float*)d_in[18];
  const float* c_g1 = (const float*)d_in[19];
  const float* c_be1 = (const float*)d_in[20];
  const float* c_w2 = (const float*)d_in[21];

  char* base = (char*)d_ws;
  size_t off = 0;
  auto alloc = [&](size_t bytes) -> void* {
    void* p = base + off;
    off = (off + bytes + 255) & ~(size_t)255;
    return p;
  };
  unsigned short* t = (unsigned short*)alloc((size_t)En * 128 * 2);      // 204.8 MB
  unsigned short* nodeA = (unsigned short*)alloc((size_t)Nn * 256 * 2);  // [h | agg] bf16
  unsigned short* hWr = (unsigned short*)alloc((size_t)Nn * 128 * 2);    // h@W1a^T + b1
  unsigned short* hWc = (unsigned short*)alloc((size_t)Nn * 128 * 2);    // h@W1b^T
  float* scaleE = (float*)alloc((size_t)En * 4);
  int* cnt = (int*)alloc((size_t)Nn * 4);
  int* startp = (int*)alloc((size_t)Nn * 4);
  int* cursor = (int*)alloc((size_t)Nn * 4);
  int* elist = (int*)alloc((size_t)En * 4);
  float* statS = (float*)alloc(4 * NSLOT * 128 * 4);
  float* statQ = (float*)alloc(4 * NSLOT * 128 * 4);
  float* bnS = (float*)alloc(4 * 128 * 4);
  float* bnSh = (float*)alloc(4 * 128 * 4);
  unsigned short* w1a = (unsigned short*)alloc(128 * 128 * 2);
  unsigned short* w1b = (unsigned short*)alloc(128 * 128 * 2);
  unsigned short* w2b = (unsigned short*)alloc(128 * 128 * 2);
  unsigned short* c1b = (unsigned short*)alloc(128 * 128 * 2);
  unsigned short* n1b = (unsigned short*)alloc(128 * 256 * 2);
  unsigned short* n2b = (unsigned short*)alloc(128 * 128 * 2);
  float* wlast = (float*)alloc(128 * 4);

  hipMemsetAsync(cnt, 0, (size_t)Nn * 4, stream);
  hipMemsetAsync(statS, 0, 4 * NSLOT * 128 * 4, stream);
  hipMemsetAsync(statQ, 0, 4 * NSLOT * 128 * 4, stream);

  // prep: bf16 h + weights
  k_prep_h<<<(Nn * 128 + 255) / 256, 256, 0, stream>>>(h, nodeA);
  k_prep_w<<<(128 * 128 + 255) / 256, 256, 0, stream>>>(e_w1, w1a, 257, 0, 7, 128 * 128);
  k_prep_w<<<(128 * 128 + 255) / 256, 256, 0, stream>>>(e_w1, w1b, 257, 128, 7, 128 * 128);
  k_prep_w<<<(128 * 128 + 255) / 256, 256, 0, stream>>>(e_w2, w2b, 128, 0, 7, 128 * 128);
  k_prep_w<<<(128 * 128 + 255) / 256, 256, 0, stream>>>(c_w1, c1b, 128, 0, 7, 128 * 128);
  k_prep_w<<<(128 * 256 + 255) / 256, 256, 0, stream>>>(n_w1, n1b, 256, 0, 8, 128 * 256);
  k_prep_w<<<(128 * 128 + 255) / 256, 256, 0, stream>>>(n_w2, n2b, 128, 0, 7, 128 * 128);
  k_wlast<<<1, 128, 0, stream>>>(e_w1, wlast);

  // CSR build (segment id = row)
  k_count<<<En / 256, 256, 0, stream>>>(row, cnt);
  k_scan<<<1, 1024, 0, stream>>>(cnt, startp, cursor, Nn);
  k_fill<<<En / 256, 256, 0, stream>>>(row, cursor, elist);

  // factorized edge layer 1: per-node partial GEMMs (bias folded into hWr)
  const int gridN = (Nn + 127) / 128;
  k_gemmW<4, false, false, false><<<gridN, 256, 0, stream>>>(
      nodeA, 256, w1a, e_b1, nullptr, nullptr, hWr, nullptr, nullptr, nullptr, nullptr, Nn);
  k_gemmW<4, false, false, false><<<gridN, 256, 0, stream>>>(
      nodeA, 256, w1b, nullptr, nullptr, nullptr, hWc, nullptr, nullptr, nullptr, nullptr, Nn);

  // per-edge combine -> t1 + stats slot 0
  k_edge_comb<<<1280, 256, 0, stream>>>(hWr, hWc, coord, row, col, wlast, t,
                                        statS + 0 * NSLOT * 128, statQ + 0 * NSLOT * 128,
                                        1280 * 4);
  k_fin<<<1, 128, 0, stream>>>(statS + 0 * NSLOT * 128, statQ + 0 * NSLOT * 128, e_g1, e_be1,
                               1.f / En, bnS + 0, bnSh + 0);

  // edge layer 2 (in-place on t, stats slot 1)
  k_gemmW<4, true, true, false><<<En / 128, 256, 0, stream>>>(
      t, 128, w2b, e_b2, bnS + 0, bnSh + 0, t, statS + 1 * NSLOT * 128, statQ + 1 * NSLOT * 128,
      nullptr, nullptr, En);
  k_fin<<<1, 128, 0, stream>>>(statS + 1 * NSLOT * 128, statQ + 1 * NSLOT * 128, e_g2, e_be2,
                               1.f / En, bnS + 128, bnSh + 128);

  // node aggregation of edge_feat = relu(bn2(t2)) -> nodeA[:,128:]
  k_agg<<<(Nn + 3) / 4, 256, 0, stream>>>(t, elist, startp, cnt, bnS + 128, bnSh + 128, nodeA);

  // coord layer 1 (in-place on t, stats slot 2)
  k_gemmW<4, true, true, false><<<En / 128, 256, 0, stream>>>(
      t, 128, c1b, c_b1, bnS + 128, bnSh + 128, t, statS + 2 * NSLOT * 128,
      statQ + 2 * NSLOT * 128, nullptr, nullptr, En);
  k_fin<<<1, 128, 0, stream>>>(statS + 2 * NSLOT * 128, statQ + 2 * NSLOT * 128, c_g1, c_be1,
                               1.f / En, bnS + 256, bnSh + 256);

  // per-edge scalar + coord output
  k_scale<<<En / 4, 256, 0, stream>>>(t, bnS + 256, bnSh + 256, c_w2, scaleE);
  float* hout = (float*)d_out;
  float* cout = hout + (size_t)Nn * 128;
  k_coord<<<(Nn + 3) / 4, 256, 0, stream>>>(coord, col, elist, startp, cnt, scaleE, cout);

  // node MLP: l1 (stats slot 3) then l2 with fp32 residual out
  k_gemmW<8, false, true, false><<<gridN, 256, 0, stream>>>(
      nodeA, 256, n1b, n_b1, nullptr, nullptr, t, statS + 3 * NSLOT * 128,
      statQ + 3 * NSLOT * 128, nullptr, nullptr, Nn);
  k_fin<<<1, 128, 0, stream>>>(statS + 3 * NSLOT * 128, statQ + 3 * NSLOT * 128, n_g1, n_be1,
                               1.f / Nn, bnS + 384, bnSh + 384);
  k_gemmW<4, true, false, true><<<gridN, 256, 0, stream>>>(
      t, 128, n2b, n_b2, bnS + 384, bnSh + 384, nullptr, nullptr, nullptr, h, hout, Nn);
}